// Round 8
// baseline (725.452 us; speedup 1.0000x reference)
//
#include <hip/hip_runtime.h>
#include <stdint.h>

#define B_ 32
#define C_ 512
#define HW_ 4096
#define N_ 131072
#define K_ 512
#define QELEMS 67108864   /* B*C*H*W = 2^26 */
#define MARGIN 1e-3f
#define RFCAP 131072      /* == N_: refine list can never overflow */

typedef __attribute__((ext_vector_type(8)))  short bf16x8;
typedef __attribute__((ext_vector_type(16))) float f32x16;

__device__ __forceinline__ ushort f2bf(float f) {   // RNE f32->bf16 (no NaN inputs)
  uint u = __float_as_uint(f);
  return (ushort)((u + 0x7FFFu + ((u >> 16) & 1u)) >> 16);
}

// ---------------------------------------------------------------------------
// numpy float32 pairwise sum of 512 floats (AVX512 base case, 8 vec accs,
// GCC _mm512_reduce_add_ps horizontal tree).
// ---------------------------------------------------------------------------
__device__ __forceinline__ float np_pw512(const float* a) {
  float P[4];
#pragma unroll
  for (int m = 0; m < 4; ++m) {
    const float* q = a + m * 128;
    float rv[16];
#pragma unroll
    for (int l = 0; l < 16; ++l) {
      float v0 = q[l],      v1 = q[16 + l],  v2 = q[32 + l],  v3 = q[48 + l];
      float v4 = q[64 + l], v5 = q[80 + l],  v6 = q[96 + l],  v7 = q[112 + l];
      rv[l] = ((v0 + v1) + (v2 + v3)) + ((v4 + v5) + (v6 + v7));
    }
    float u[8], w[4];
#pragma unroll
    for (int l = 0; l < 8; ++l) u[l] = rv[8 + l] + rv[l];
#pragma unroll
    for (int l = 0; l < 4; ++l) w[l] = u[4 + l] + u[l];
    P[m] = (w[0] + w[2]) + (w[1] + w[3]);
  }
  return (P[0] + P[1]) + (P[2] + P[3]);
}

// Same tree over squared elements (sq computed with __fmul_rn, as np does).
__device__ __forceinline__ float np_pw512_sq(const float* a) {
  float P[4];
#pragma unroll
  for (int m = 0; m < 4; ++m) {
    const float* q = a + m * 128;
    float rv[16];
#pragma unroll
    for (int l = 0; l < 16; ++l) {
      float v0 = __fmul_rn(q[l], q[l]);
      float v1 = __fmul_rn(q[16 + l], q[16 + l]);
      float v2 = __fmul_rn(q[32 + l], q[32 + l]);
      float v3 = __fmul_rn(q[48 + l], q[48 + l]);
      float v4 = __fmul_rn(q[64 + l], q[64 + l]);
      float v5 = __fmul_rn(q[80 + l], q[80 + l]);
      float v6 = __fmul_rn(q[96 + l], q[96 + l]);
      float v7 = __fmul_rn(q[112 + l], q[112 + l]);
      rv[l] = ((v0 + v1) + (v2 + v3)) + ((v4 + v5) + (v6 + v7));
    }
    float u[8], w[4];
#pragma unroll
    for (int l = 0; l < 8; ++l) u[l] = rv[8 + l] + rv[l];
#pragma unroll
    for (int l = 0; l < 4; ++l) w[l] = u[4 + l] + u[l];
    P[m] = (w[0] + w[2]) + (w[1] + w[3]);
  }
  return (P[0] + P[1]) + (P[2] + P[3]);
}

// ---------------------------------------------------------------------------
// K0: e1p[k][c] = bf16(embed); senp[k] = np-f32 pairwise sum of e^2; rcnt=0.
// ---------------------------------------------------------------------------
__global__ __launch_bounds__(256) void k_prep(const float* __restrict__ embed,
    ushort* __restrict__ e1p, float* __restrict__ senp, int* __restrict__ rcnt)
{
  __shared__ float sqa[C_];
  int k = blockIdx.x;
  for (int c = threadIdx.x; c < C_; c += 256) {
    float e = embed[k * C_ + c];
    e1p[k * C_ + c] = f2bf(e);
    sqa[c] = __fmul_rn(e, e);
  }
  __syncthreads();
  if (threadIdx.x == 0) {
    senp[k] = np_pw512(sqa);
    if (blockIdx.x == 0) *rcnt = 0;
  }
}

// ---------------------------------------------------------------------------
// K0b: x [b][c][hw] f32  ->  x1p [b][hw][c] bf16 (transpose via LDS tile).
// ---------------------------------------------------------------------------
__global__ __launch_bounds__(256) void k_xsplit(const float* __restrict__ x,
    ushort* __restrict__ x1p)
{
  __shared__ ushort tile[64][66];
  const int bid = blockIdx.x;
  const int ht = bid & 63, ct = (bid >> 6) & 7, b = bid >> 9;
  const int t = threadIdx.x;
  const int r = t & 63, cq = t >> 6;
  const float* xp = x + (((size_t)(b * C_ + ct * 64)) << 12) + ht * 64 + r;
#pragma unroll
  for (int i = 0; i < 16; ++i) {
    int c = cq * 16 + i;
    tile[r][c] = f2bf(xp[(size_t)c << 12]);
  }
  __syncthreads();
  const int r2 = t >> 2, cs = (t & 3) << 4;
  uint w[8];
#pragma unroll
  for (int j = 0; j < 8; ++j)
    w[j] = *(const uint*)&tile[r2][cs + 2 * j];
  ushort* op = x1p + (((size_t)(b * HW_ + ht * 64 + r2)) << 9) + ct * 64 + cs;
  ((uint4*)op)[0] = make_uint4(w[0], w[1], w[2], w[3]);
  ((uint4*)op)[1] = make_uint4(w[4], w[5], w[6], w[7]);
}

// ---------------------------------------------------------------------------
// K1: MFMA argmin with depth-4 register prefetch pipeline.
//     Layout/merge logic identical to the verified round-6 kernel; only the
//     K-loop schedule changed (loads hoisted 4 iterations ahead so ~20
//     16B loads stay in flight instead of drain-every-iteration).
// ---------------------------------------------------------------------------
__global__ __launch_bounds__(512) void k_argmin(const ushort* __restrict__ x1p,
    const ushort* __restrict__ e1p, const float* __restrict__ senp,
    int* __restrict__ idx_out, int* __restrict__ rcnt, int* __restrict__ rrows)
{
  __shared__ float ses[K_];
  __shared__ float mbL[64][4], msL[64][4];
  __shared__ int   miL[64][4];
  const int t = threadIdx.x;
  const int lane = t & 63, wid = t >> 6;
  const int wc = wid & 3, wr = wid >> 2;
  const int l31 = lane & 31, lhi = lane >> 5;
  const int b = blockIdx.x >> 6;
  const int rowt = blockIdx.x & 63;

  for (int i = t; i < K_; i += 512) ses[i] = senp[i];
  __syncthreads();

  const bf16x8* xp =
      (const bf16x8*)(x1p + (((size_t)(b * HW_ + rowt * 64 + wr * 32 + l31)) << 9)
                      + 8 * lhi);
  const size_t eb = (((size_t)(wc * 128 + l31)) << 9) + 8 * lhi;
  const bf16x8* ep0 = (const bf16x8*)(e1p + eb);
  const bf16x8* ep1 = (const bf16x8*)(e1p + eb + (32 << 9));
  const bf16x8* ep2 = (const bf16x8*)(e1p + eb + (64 << 9));
  const bf16x8* ep3 = (const bf16x8*)(e1p + eb + (96 << 9));

  f32x16 a0 = {0,0,0,0,0,0,0,0,0,0,0,0,0,0,0,0};
  f32x16 a1 = a0, a2 = a0, a3 = a0;

  // depth-4 rotation buffers; fully unrolled => all indices constant-folded
  bf16x8 X[4], E0[4], E1[4], E2[4], E3[4];
#pragma unroll
  for (int p = 0; p < 4; ++p) {
    X[p]  = xp[2 * p];
    E0[p] = ep0[2 * p]; E1[p] = ep1[2 * p];
    E2[p] = ep2[2 * p]; E3[p] = ep3[2 * p];
  }
#pragma unroll
  for (int ks = 0; ks < 32; ++ks) {
    const int cur = ks & 3;
    a0 = __builtin_amdgcn_mfma_f32_32x32x16_bf16(E0[cur], X[cur], a0, 0, 0, 0);
    a1 = __builtin_amdgcn_mfma_f32_32x32x16_bf16(E1[cur], X[cur], a1, 0, 0, 0);
    a2 = __builtin_amdgcn_mfma_f32_32x32x16_bf16(E2[cur], X[cur], a2, 0, 0, 0);
    a3 = __builtin_amdgcn_mfma_f32_32x32x16_bf16(E3[cur], X[cur], a3, 0, 0, 0);
    if (ks + 4 < 32) {
      X[cur]  = xp[2 * (ks + 4)];
      E0[cur] = ep0[2 * (ks + 4)]; E1[cur] = ep1[2 * (ks + 4)];
      E2[cur] = ep2[2 * (ks + 4)]; E3[cur] = ep3[2 * (ks + 4)];
    }
  }

  float best = 1e30f, second = 1e30f; int bidx = 0;
#pragma unroll
  for (int r = 0; r < 16; ++r) {
    int crow = (r & 3) + 8 * (r >> 2) + 4 * lhi;
    float v; int code;
    code = wc * 128 + 0  + crow; v = ses[code] - 2.0f * a0[r];
    if (v < best || (v == best && code < bidx)) { second = best; best = v; bidx = code; }
    else if (v < second) second = v;
    code = wc * 128 + 32 + crow; v = ses[code] - 2.0f * a1[r];
    if (v < best || (v == best && code < bidx)) { second = best; best = v; bidx = code; }
    else if (v < second) second = v;
    code = wc * 128 + 64 + crow; v = ses[code] - 2.0f * a2[r];
    if (v < best || (v == best && code < bidx)) { second = best; best = v; bidx = code; }
    else if (v < second) second = v;
    code = wc * 128 + 96 + crow; v = ses[code] - 2.0f * a3[r];
    if (v < best || (v == best && code < bidx)) { second = best; best = v; bidx = code; }
    else if (v < second) second = v;
  }
  {
    float ob = __shfl_xor(best, 32, 64);
    float os = __shfl_xor(second, 32, 64);
    int   oi = __shfl_xor(bidx, 32, 64);
    float ns = fminf(fmaxf(best, ob), fminf(second, os));
    if (ob < best || (ob == best && oi < bidx)) { best = ob; bidx = oi; }
    second = ns;
  }
  if (lane < 32) {
    int rr = wr * 32 + l31;
    mbL[rr][wc] = best; msL[rr][wc] = second; miL[rr][wc] = bidx;
  }
  __syncthreads();
  if (t < 64) {
    float Bv = 1e30f, Sv = 1e30f; int Iv = 0;
#pragma unroll
    for (int q = 0; q < 4; ++q) {
      float b1 = mbL[t][q], s1 = msL[t][q]; int i1 = miL[t][q];
      if (b1 < Bv || (b1 == Bv && i1 < Iv)) { Sv = fminf(Bv, s1); Bv = b1; Iv = i1; }
      else Sv = fminf(Sv, b1);
    }
    int n = b * HW_ + rowt * 64 + t;
    idx_out[n] = Iv;
    if (Sv - Bv < MARGIN) {
      int p = atomicAdd(rcnt, 1);
      if (p < RFCAP) rrows[p] = n;
    }
  }
}

// ---------------------------------------------------------------------------
// K2: np-f32-replica re-rank, 8 rows per block batch (unchanged, verified).
// ---------------------------------------------------------------------------
__global__ __launch_bounds__(512) void k_refine(const float* __restrict__ x,
    const float* __restrict__ embed, const float* __restrict__ senp,
    const int* __restrict__ rcnt, const int* __restrict__ rrows,
    int* __restrict__ idx_out)
{
  __shared__ float xls[8][520];
  __shared__ float SxSh[8];
  __shared__ int   nrow[8];
  __shared__ float wval[8][8];
  __shared__ int   widx[8][8];
  const int t = threadIdx.x;
  const int lane = t & 63, w = t >> 6;
  int cnt = *rcnt; if (cnt > RFCAP) cnt = RFCAP;
  for (int base = blockIdx.x * 8; base < cnt; base += gridDim.x * 8) {
    __syncthreads();
    if (t < 8) {
      int i = base + t;
      nrow[t] = rrows[i < cnt ? i : base];
    }
    __syncthreads();
#pragma unroll
    for (int rr = 0; rr < 8; ++rr) {
      int n = nrow[rr];
      int b = n >> 12, hw = n & 4095;
      xls[rr][t] = x[(((size_t)(b * C_ + t)) << 12) + hw];
    }
    __syncthreads();
    if (t < 8) SxSh[t] = np_pw512_sq(&xls[t][0]);
    __syncthreads();
    const float* e = embed + (size_t)t * C_;
    float a1[8], a2[8];
#pragma unroll
    for (int rr = 0; rr < 8; ++rr) { a1[rr] = 0.f; a2[rr] = 0.f; }
    for (int c4 = 0; c4 < 384; c4 += 4) {
      float4 ev = *(const float4*)(e + c4);
#pragma unroll
      for (int rr = 0; rr < 8; ++rr) {
        float4 xv = *(const float4*)&xls[rr][c4];
        a1[rr] = fmaf(xv.x, ev.x, a1[rr]);
        a1[rr] = fmaf(xv.y, ev.y, a1[rr]);
        a1[rr] = fmaf(xv.z, ev.z, a1[rr]);
        a1[rr] = fmaf(xv.w, ev.w, a1[rr]);
      }
    }
    for (int c4 = 384; c4 < 512; c4 += 4) {
      float4 ev = *(const float4*)(e + c4);
#pragma unroll
      for (int rr = 0; rr < 8; ++rr) {
        float4 xv = *(const float4*)&xls[rr][c4];
        a2[rr] = fmaf(xv.x, ev.x, a2[rr]);
        a2[rr] = fmaf(xv.y, ev.y, a2[rr]);
        a2[rr] = fmaf(xv.z, ev.z, a2[rr]);
        a2[rr] = fmaf(xv.w, ev.w, a2[rr]);
      }
    }
    float se = senp[t];
    float bv[8]; int bi[8];
#pragma unroll
    for (int rr = 0; rr < 8; ++rr) {
      float M = a1[rr] + a2[rr];
      bv[rr] = (SxSh[rr] + se) - 2.0f * M;
      bi[rr] = t;
    }
#pragma unroll
    for (int off = 1; off < 64; off <<= 1) {
#pragma unroll
      for (int rr = 0; rr < 8; ++rr) {
        float ov = __shfl_xor(bv[rr], off, 64);
        int   oi = __shfl_xor(bi[rr], off, 64);
        if (ov < bv[rr] || (ov == bv[rr] && oi < bi[rr])) { bv[rr] = ov; bi[rr] = oi; }
      }
    }
    if (lane == 0) {
#pragma unroll
      for (int rr = 0; rr < 8; ++rr) { wval[w][rr] = bv[rr]; widx[w][rr] = bi[rr]; }
    }
    __syncthreads();
    if (t < 8) {
      float Bv = wval[0][t]; int Iv = widx[0][t];
#pragma unroll
      for (int q = 1; q < 8; ++q) {
        float ov = wval[q][t]; int oi = widx[q][t];
        if (ov < Bv || (ov == Bv && oi < Iv)) { Bv = ov; Iv = oi; }
      }
      if (base + t < cnt) idx_out[nrow[t]] = Iv;
    }
  }
}

// ---------------------------------------------------------------------------
// K3: gather + loss (unchanged).
// ---------------------------------------------------------------------------
__global__ __launch_bounds__(256) void k_gather(const float* __restrict__ x,
    const float* __restrict__ embed, const int* __restrict__ idx,
    float* __restrict__ out_q, double* __restrict__ loss_part)
{
  __shared__ float ecol[32][512];
  const int bid = blockIdx.x;
  const int hch = bid & 1, cch = (bid >> 1) & 15, b = bid >> 5;
  const int c0 = cch * 32, hw0 = hch * 2048;
  const int t = threadIdx.x;
  for (int i = t; i < 512 * 32; i += 256) {
    int c = i & 31, k = i >> 5;
    ecol[c][(k + c0 + c) & 511] = embed[((size_t)k << 9) + c0 + c];
  }
  __syncthreads();
  int kreg[8];
#pragma unroll
  for (int j = 0; j < 8; ++j)
    kreg[j] = idx[(b << 12) + hw0 + t + 256 * j];
  double s = 0.0;
  for (int c = 0; c < 32; ++c) {
    const float* xrow = x + (((size_t)(b * C_ + c0 + c)) << 12) + hw0;
    float* orow = out_q + (((size_t)(b * C_ + c0 + c)) << 12) + hw0;
#pragma unroll
    for (int j = 0; j < 8; ++j) {
      float q  = ecol[c][(kreg[j] + c0 + c) & 511];
      float xv = xrow[t + 256 * j];
      orow[t + 256 * j] = q;
      double d = (double)q - (double)xv;
      s += d * d;
    }
  }
  for (int off = 32; off > 0; off >>= 1) s += __shfl_down(s, off, 64);
  __shared__ double wsum[4];
  if ((t & 63) == 0) wsum[t >> 6] = s;
  __syncthreads();
  if (t == 0)
    loss_part[bid] = (wsum[0] + wsum[1]) + (wsum[2] + wsum[3]);
}

// ---------------------------------------------------------------------------
// K4: per-batch unique-code count + write idx_b as float.
// ---------------------------------------------------------------------------
__global__ __launch_bounds__(256) void k_pplx(const int* __restrict__ idx,
    float* __restrict__ out_idxf, int* __restrict__ counts)
{
  __shared__ int flags[K_];
  __shared__ int red[256];
  int b = blockIdx.x;
  for (int i = threadIdx.x; i < K_; i += 256) flags[i] = 0;
  __syncthreads();
  for (int hw = threadIdx.x; hw < HW_; hw += 256) {
    int k = idx[(b << 12) + hw];
    flags[k] = 1;
    out_idxf[(b << 12) + hw] = (float)k;
  }
  __syncthreads();
  int c = 0;
  for (int i = threadIdx.x; i < K_; i += 256) c += flags[i];
  red[threadIdx.x] = c;
  __syncthreads();
  for (int st = 128; st > 0; st >>= 1) {
    if (threadIdx.x < st) red[threadIdx.x] += red[threadIdx.x + st];
    __syncthreads();
  }
  if (threadIdx.x == 0) counts[b] = red[0];
}

// ---------------------------------------------------------------------------
// K5: finalize scalars (1024 loss partials).
// ---------------------------------------------------------------------------
__global__ __launch_bounds__(256) void k_final(const double* __restrict__ loss_part,
    const int* __restrict__ counts, float* __restrict__ out_loss,
    float* __restrict__ out_pplx)
{
  __shared__ double sred[256];
  double s = 0.0;
  for (int i = threadIdx.x; i < 1024; i += 256) s += loss_part[i];
  sred[threadIdx.x] = s;
  __syncthreads();
  for (int st = 128; st > 0; st >>= 1) {
    if (threadIdx.x < st) sred[threadIdx.x] += sred[threadIdx.x + st];
    __syncthreads();
  }
  if (threadIdx.x == 0) {
    *out_loss = (float)(1.25 * sred[0] / (double)QELEMS);
    int c = 0;
    for (int i = 0; i < B_; ++i) c += counts[i];
    *out_pplx = (float)c / (float)B_;
  }
}

// ---------------------------------------------------------------------------
extern "C" void kernel_launch(void* const* d_in, const int* in_sizes, int n_in,
                              void* d_out, int out_size, void* d_ws, size_t ws_size,
                              hipStream_t stream)
{
  const float* x     = (const float*)d_in[0];
  const float* embed = (const float*)d_in[1];
  float* out      = (float*)d_out;
  float* out_loss = out;                  // [0]
  float* out_q    = out + 1;              // [1 .. 1+QELEMS)
  float* out_pplx = out + 1 + QELEMS;     // [1+QELEMS]
  float* out_idxf = out + 2 + QELEMS;     // [2+QELEMS ..)

  char* ws = (char*)d_ws;
  int*    w_idx = (int*)ws;
  double* w_lp  = (double*)(ws + 524288);
  int*    w_cnt = (int*)(ws + 524288 + 16384);
  size_t pers = 524288 + 16384 + 128;

  const size_t OFF_E1P  = 134217728;
  const size_t OFF_SENP = OFF_E1P + 524288;
  const size_t OFF_RCNT = OFF_SENP + 2048;
  const size_t OFF_RROW = OFF_RCNT + 256;
  const size_t VOLB     = OFF_RROW + (size_t)RFCAP * 4;
  char* vbase;
  if (ws_size >= pers + VOLB + 4096) {
    vbase = ws + ((pers + 255) & ~(size_t)255);
  } else {
    uintptr_t a = ((uintptr_t)(out_q + QELEMS) - VOLB) & ~(uintptr_t)255;
    vbase = (char*)a;
  }
  ushort* w_x1p  = (ushort*)vbase;
  ushort* w_e1p  = (ushort*)(vbase + OFF_E1P);
  float*  w_senp = (float*)(vbase + OFF_SENP);
  int*    w_rcnt = (int*)(vbase + OFF_RCNT);
  int*    w_rrows= (int*)(vbase + OFF_RROW);

  k_prep  <<<dim3(512),   dim3(256), 0, stream>>>(embed, w_e1p, w_senp, w_rcnt);
  k_xsplit<<<dim3(16384), dim3(256), 0, stream>>>(x, w_x1p);
  k_argmin<<<dim3(2048),  dim3(512), 0, stream>>>(w_x1p, w_e1p, w_senp, w_idx, w_rcnt, w_rrows);
  k_refine<<<dim3(2048),  dim3(512), 0, stream>>>(x, embed, w_senp, w_rcnt, w_rrows, w_idx);
  k_gather<<<dim3(1024),  dim3(256), 0, stream>>>(x, embed, w_idx, out_q, w_lp);
  k_pplx  <<<dim3(32),    dim3(256), 0, stream>>>(w_idx, out_idxf, w_cnt);
  k_final <<<dim3(1),     dim3(256), 0, stream>>>(w_lp, w_cnt, out_loss, out_pplx);
}

// Round 9
// 559.863 us; speedup vs baseline: 1.2958x; 1.2958x over previous
//
#include <hip/hip_runtime.h>
#include <stdint.h>

#define B_ 32
#define C_ 512
#define HW_ 4096
#define N_ 131072
#define K_ 512
#define QELEMS 67108864   /* B*C*H*W = 2^26 */
#define MARGIN 1e-3f
#define RFCAP 131072      /* == N_: refine list can never overflow */

typedef __attribute__((ext_vector_type(8)))  short bf16x8;
typedef __attribute__((ext_vector_type(16))) float f32x16;

__device__ __forceinline__ ushort f2bf(float f) {   // RNE f32->bf16 (no NaN inputs)
  uint u = __float_as_uint(f);
  return (ushort)((u + 0x7FFFu + ((u >> 16) & 1u)) >> 16);
}

// ---------------------------------------------------------------------------
// numpy float32 pairwise sum of 512 floats (AVX512 base case, 8 vec accs,
// GCC _mm512_reduce_add_ps horizontal tree).
// ---------------------------------------------------------------------------
__device__ __forceinline__ float np_pw512(const float* a) {
  float P[4];
#pragma unroll
  for (int m = 0; m < 4; ++m) {
    const float* q = a + m * 128;
    float rv[16];
#pragma unroll
    for (int l = 0; l < 16; ++l) {
      float v0 = q[l],      v1 = q[16 + l],  v2 = q[32 + l],  v3 = q[48 + l];
      float v4 = q[64 + l], v5 = q[80 + l],  v6 = q[96 + l],  v7 = q[112 + l];
      rv[l] = ((v0 + v1) + (v2 + v3)) + ((v4 + v5) + (v6 + v7));
    }
    float u[8], w[4];
#pragma unroll
    for (int l = 0; l < 8; ++l) u[l] = rv[8 + l] + rv[l];
#pragma unroll
    for (int l = 0; l < 4; ++l) w[l] = u[4 + l] + u[l];
    P[m] = (w[0] + w[2]) + (w[1] + w[3]);
  }
  return (P[0] + P[1]) + (P[2] + P[3]);
}

// Same tree over squared elements (sq computed with __fmul_rn, as np does).
__device__ __forceinline__ float np_pw512_sq(const float* a) {
  float P[4];
#pragma unroll
  for (int m = 0; m < 4; ++m) {
    const float* q = a + m * 128;
    float rv[16];
#pragma unroll
    for (int l = 0; l < 16; ++l) {
      float v0 = __fmul_rn(q[l], q[l]);
      float v1 = __fmul_rn(q[16 + l], q[16 + l]);
      float v2 = __fmul_rn(q[32 + l], q[32 + l]);
      float v3 = __fmul_rn(q[48 + l], q[48 + l]);
      float v4 = __fmul_rn(q[64 + l], q[64 + l]);
      float v5 = __fmul_rn(q[80 + l], q[80 + l]);
      float v6 = __fmul_rn(q[96 + l], q[96 + l]);
      float v7 = __fmul_rn(q[112 + l], q[112 + l]);
      rv[l] = ((v0 + v1) + (v2 + v3)) + ((v4 + v5) + (v6 + v7));
    }
    float u[8], w[4];
#pragma unroll
    for (int l = 0; l < 8; ++l) u[l] = rv[8 + l] + rv[l];
#pragma unroll
    for (int l = 0; l < 4; ++l) w[l] = u[4 + l] + u[l];
    P[m] = (w[0] + w[2]) + (w[1] + w[3]);
  }
  return (P[0] + P[1]) + (P[2] + P[3]);
}

// ---------------------------------------------------------------------------
// K0: senp[k] = np-f32 pairwise sum of e^2; rcnt=0.
// ---------------------------------------------------------------------------
__global__ __launch_bounds__(256) void k_prep(const float* __restrict__ embed,
    float* __restrict__ senp, int* __restrict__ rcnt)
{
  __shared__ float sqa[C_];
  int k = blockIdx.x;
  for (int c = threadIdx.x; c < C_; c += 256) {
    float e = embed[k * C_ + c];
    sqa[c] = __fmul_rn(e, e);
  }
  __syncthreads();
  if (threadIdx.x == 0) {
    senp[k] = np_pw512(sqa);
    if (blockIdx.x == 0) *rcnt = 0;
  }
}

// ---------------------------------------------------------------------------
// K0a: pack embed -> efrag fragment-major:
//   efrag[((cb*32+ks)*64 + lane)*8 + j] = bf16(embed[cb*32+(lane&31)]
//                                                   [ks*16+(lane>>5)*8+j])
//   (cb = 32-code block 0..15, ks = 16-c step 0..31). 16 blocks x 256 thr.
// ---------------------------------------------------------------------------
__global__ __launch_bounds__(256) void k_epack(const float* __restrict__ embed,
    ushort* __restrict__ efrag)
{
  const int cb = blockIdx.x;
  const int t = threadIdx.x;
  const int lane = t & 63, ksq = t >> 6;
  const int l31 = lane & 31, lhi = lane >> 5;
  const float* ep = embed + ((size_t)(cb * 32 + l31) << 9) + lhi * 8;
#pragma unroll
  for (int i = 0; i < 8; ++i) {
    int ks = ksq * 8 + i;
    float4 v0 = *(const float4*)(ep + ks * 16);
    float4 v1 = *(const float4*)(ep + ks * 16 + 4);
    uint u0 = (uint)f2bf(v0.x) | ((uint)f2bf(v0.y) << 16);
    uint u1 = (uint)f2bf(v0.z) | ((uint)f2bf(v0.w) << 16);
    uint u2 = (uint)f2bf(v1.x) | ((uint)f2bf(v1.y) << 16);
    uint u3 = (uint)f2bf(v1.z) | ((uint)f2bf(v1.w) << 16);
    ushort* op = efrag + (((size_t)(cb * 32 + ks)) * 64 + lane) * 8;
    *(uint4*)op = make_uint4(u0, u1, u2, u3);
  }
}

// ---------------------------------------------------------------------------
// K0b: x [b][c][hw] f32 -> xfrag fragment-major bf16:
//   xfrag[((rb*32+ks)*64 + lane)*8 + j] = bf16(x[b][ks*16+(lane>>5)*8+j]
//                                               [rb*32+(lane&31)])
//   rb = global 32-row block (b*128 + hw>>5). Same LDS transpose as before;
//   only the output addressing changed (writes stay 1KB wave-coalesced).
// ---------------------------------------------------------------------------
__global__ __launch_bounds__(256) void k_xsplit(const float* __restrict__ x,
    ushort* __restrict__ xfrag)
{
  __shared__ ushort tile[64][66];
  const int bid = blockIdx.x;
  const int ht = bid & 63, ct = (bid >> 6) & 7, b = bid >> 9;
  const int t = threadIdx.x;
  const int r = t & 63, cq = t >> 6;
  const float* xp = x + (((size_t)(b * C_ + ct * 64)) << 12) + ht * 64 + r;
#pragma unroll
  for (int i = 0; i < 16; ++i) {
    int c = cq * 16 + i;
    tile[r][c] = f2bf(xp[(size_t)c << 12]);
  }
  __syncthreads();
  const int lane = t & 63, ksl = t >> 6;       // ks_local 0..3
  const int l31 = lane & 31, lhi = lane >> 5;
  const int ks = ct * 4 + ksl;                 // global ks 0..31
  const int cc = ksl * 16 + lhi * 8;
#pragma unroll
  for (int rbl = 0; rbl < 2; ++rbl) {
    int rr = rbl * 32 + l31;
    uint w0 = *(const uint*)&tile[rr][cc + 0];
    uint w1 = *(const uint*)&tile[rr][cc + 2];
    uint w2 = *(const uint*)&tile[rr][cc + 4];
    uint w3 = *(const uint*)&tile[rr][cc + 6];
    size_t rb = (size_t)b * 128 + ht * 2 + rbl;
    ushort* op = xfrag + ((rb * 32 + ks) * 64 + lane) * 8;
    *(uint4*)op = make_uint4(w0, w1, w2, w3);
  }
}

// ---------------------------------------------------------------------------
// K1: MFMA argmin, fragment-major operands (all loads 1KB wave-coalesced).
//     MFMA lane mapping identical to the verified round-6 kernel.
// ---------------------------------------------------------------------------
__global__ __launch_bounds__(512) void k_argmin(const ushort* __restrict__ xfrag,
    const ushort* __restrict__ efrag, const float* __restrict__ senp,
    int* __restrict__ idx_out, int* __restrict__ rcnt, int* __restrict__ rrows)
{
  __shared__ float ses[K_];
  __shared__ float mbL[64][4], msL[64][4];
  __shared__ int   miL[64][4];
  const int t = threadIdx.x;
  const int lane = t & 63, wid = t >> 6;
  const int wc = wid & 3, wr = wid >> 2;
  const int l31 = lane & 31, lhi = lane >> 5;
  const int b = blockIdx.x >> 6;
  const int rowt = blockIdx.x & 63;

  for (int i = t; i < K_; i += 512) ses[i] = senp[i];
  __syncthreads();

  const size_t rb = (size_t)b * 128 + rowt * 2 + wr;
  const bf16x8* xq  = (const bf16x8*)xfrag + rb * 32 * 64 + lane;
  const bf16x8* eq0 = (const bf16x8*)efrag + (size_t)(wc * 4 + 0) * 32 * 64 + lane;
  const bf16x8* eq1 = (const bf16x8*)efrag + (size_t)(wc * 4 + 1) * 32 * 64 + lane;
  const bf16x8* eq2 = (const bf16x8*)efrag + (size_t)(wc * 4 + 2) * 32 * 64 + lane;
  const bf16x8* eq3 = (const bf16x8*)efrag + (size_t)(wc * 4 + 3) * 32 * 64 + lane;

  f32x16 a0 = {0,0,0,0,0,0,0,0,0,0,0,0,0,0,0,0};
  f32x16 a1 = a0, a2 = a0, a3 = a0;
#pragma unroll 8
  for (int ks = 0; ks < 32; ++ks) {
    bf16x8 xf = xq[ks * 64];
    a0 = __builtin_amdgcn_mfma_f32_32x32x16_bf16(eq0[ks * 64], xf, a0, 0, 0, 0);
    a1 = __builtin_amdgcn_mfma_f32_32x32x16_bf16(eq1[ks * 64], xf, a1, 0, 0, 0);
    a2 = __builtin_amdgcn_mfma_f32_32x32x16_bf16(eq2[ks * 64], xf, a2, 0, 0, 0);
    a3 = __builtin_amdgcn_mfma_f32_32x32x16_bf16(eq3[ks * 64], xf, a3, 0, 0, 0);
  }

  float best = 1e30f, second = 1e30f; int bidx = 0;
#pragma unroll
  for (int r = 0; r < 16; ++r) {
    int crow = (r & 3) + 8 * (r >> 2) + 4 * lhi;
    float v; int code;
    code = wc * 128 + 0  + crow; v = ses[code] - 2.0f * a0[r];
    if (v < best || (v == best && code < bidx)) { second = best; best = v; bidx = code; }
    else if (v < second) second = v;
    code = wc * 128 + 32 + crow; v = ses[code] - 2.0f * a1[r];
    if (v < best || (v == best && code < bidx)) { second = best; best = v; bidx = code; }
    else if (v < second) second = v;
    code = wc * 128 + 64 + crow; v = ses[code] - 2.0f * a2[r];
    if (v < best || (v == best && code < bidx)) { second = best; best = v; bidx = code; }
    else if (v < second) second = v;
    code = wc * 128 + 96 + crow; v = ses[code] - 2.0f * a3[r];
    if (v < best || (v == best && code < bidx)) { second = best; best = v; bidx = code; }
    else if (v < second) second = v;
  }
  {
    float ob = __shfl_xor(best, 32, 64);
    float os = __shfl_xor(second, 32, 64);
    int   oi = __shfl_xor(bidx, 32, 64);
    float ns = fminf(fmaxf(best, ob), fminf(second, os));
    if (ob < best || (ob == best && oi < bidx)) { best = ob; bidx = oi; }
    second = ns;
  }
  if (lane < 32) {
    int rr = wr * 32 + l31;
    mbL[rr][wc] = best; msL[rr][wc] = second; miL[rr][wc] = bidx;
  }
  __syncthreads();
  if (t < 64) {
    float Bv = 1e30f, Sv = 1e30f; int Iv = 0;
#pragma unroll
    for (int q = 0; q < 4; ++q) {
      float b1 = mbL[t][q], s1 = msL[t][q]; int i1 = miL[t][q];
      if (b1 < Bv || (b1 == Bv && i1 < Iv)) { Sv = fminf(Bv, s1); Bv = b1; Iv = i1; }
      else Sv = fminf(Sv, b1);
    }
    int n = b * HW_ + rowt * 64 + t;
    idx_out[n] = Iv;
    if (Sv - Bv < MARGIN) {
      int p = atomicAdd(rcnt, 1);
      if (p < RFCAP) rrows[p] = n;
    }
  }
}

// ---------------------------------------------------------------------------
// K2: np-f32-replica re-rank, 8 rows per block batch (unchanged, verified).
// ---------------------------------------------------------------------------
__global__ __launch_bounds__(512) void k_refine(const float* __restrict__ x,
    const float* __restrict__ embed, const float* __restrict__ senp,
    const int* __restrict__ rcnt, const int* __restrict__ rrows,
    int* __restrict__ idx_out)
{
  __shared__ float xls[8][520];
  __shared__ float SxSh[8];
  __shared__ int   nrow[8];
  __shared__ float wval[8][8];
  __shared__ int   widx[8][8];
  const int t = threadIdx.x;
  const int lane = t & 63, w = t >> 6;
  int cnt = *rcnt; if (cnt > RFCAP) cnt = RFCAP;
  for (int base = blockIdx.x * 8; base < cnt; base += gridDim.x * 8) {
    __syncthreads();
    if (t < 8) {
      int i = base + t;
      nrow[t] = rrows[i < cnt ? i : base];
    }
    __syncthreads();
#pragma unroll
    for (int rr = 0; rr < 8; ++rr) {
      int n = nrow[rr];
      int b = n >> 12, hw = n & 4095;
      xls[rr][t] = x[(((size_t)(b * C_ + t)) << 12) + hw];
    }
    __syncthreads();
    if (t < 8) SxSh[t] = np_pw512_sq(&xls[t][0]);
    __syncthreads();
    const float* e = embed + (size_t)t * C_;
    float a1[8], a2[8];
#pragma unroll
    for (int rr = 0; rr < 8; ++rr) { a1[rr] = 0.f; a2[rr] = 0.f; }
    for (int c4 = 0; c4 < 384; c4 += 4) {
      float4 ev = *(const float4*)(e + c4);
#pragma unroll
      for (int rr = 0; rr < 8; ++rr) {
        float4 xv = *(const float4*)&xls[rr][c4];
        a1[rr] = fmaf(xv.x, ev.x, a1[rr]);
        a1[rr] = fmaf(xv.y, ev.y, a1[rr]);
        a1[rr] = fmaf(xv.z, ev.z, a1[rr]);
        a1[rr] = fmaf(xv.w, ev.w, a1[rr]);
      }
    }
    for (int c4 = 384; c4 < 512; c4 += 4) {
      float4 ev = *(const float4*)(e + c4);
#pragma unroll
      for (int rr = 0; rr < 8; ++rr) {
        float4 xv = *(const float4*)&xls[rr][c4];
        a2[rr] = fmaf(xv.x, ev.x, a2[rr]);
        a2[rr] = fmaf(xv.y, ev.y, a2[rr]);
        a2[rr] = fmaf(xv.z, ev.z, a2[rr]);
        a2[rr] = fmaf(xv.w, ev.w, a2[rr]);
      }
    }
    float se = senp[t];
    float bv[8]; int bi[8];
#pragma unroll
    for (int rr = 0; rr < 8; ++rr) {
      float M = a1[rr] + a2[rr];
      bv[rr] = (SxSh[rr] + se) - 2.0f * M;
      bi[rr] = t;
    }
#pragma unroll
    for (int off = 1; off < 64; off <<= 1) {
#pragma unroll
      for (int rr = 0; rr < 8; ++rr) {
        float ov = __shfl_xor(bv[rr], off, 64);
        int   oi = __shfl_xor(bi[rr], off, 64);
        if (ov < bv[rr] || (ov == bv[rr] && oi < bi[rr])) { bv[rr] = ov; bi[rr] = oi; }
      }
    }
    if (lane == 0) {
#pragma unroll
      for (int rr = 0; rr < 8; ++rr) { wval[w][rr] = bv[rr]; widx[w][rr] = bi[rr]; }
    }
    __syncthreads();
    if (t < 8) {
      float Bv = wval[0][t]; int Iv = widx[0][t];
#pragma unroll
      for (int q = 1; q < 8; ++q) {
        float ov = wval[q][t]; int oi = widx[q][t];
        if (ov < Bv || (ov == Bv && oi < Iv)) { Bv = ov; Iv = oi; }
      }
      if (base + t < cnt) idx_out[nrow[t]] = Iv;
    }
  }
}

// ---------------------------------------------------------------------------
// K3: gather + loss (unchanged).
// ---------------------------------------------------------------------------
__global__ __launch_bounds__(256) void k_gather(const float* __restrict__ x,
    const float* __restrict__ embed, const int* __restrict__ idx,
    float* __restrict__ out_q, double* __restrict__ loss_part)
{
  __shared__ float ecol[32][512];
  const int bid = blockIdx.x;
  const int hch = bid & 1, cch = (bid >> 1) & 15, b = bid >> 5;
  const int c0 = cch * 32, hw0 = hch * 2048;
  const int t = threadIdx.x;
  for (int i = t; i < 512 * 32; i += 256) {
    int c = i & 31, k = i >> 5;
    ecol[c][(k + c0 + c) & 511] = embed[((size_t)k << 9) + c0 + c];
  }
  __syncthreads();
  int kreg[8];
#pragma unroll
  for (int j = 0; j < 8; ++j)
    kreg[j] = idx[(b << 12) + hw0 + t + 256 * j];
  double s = 0.0;
  for (int c = 0; c < 32; ++c) {
    const float* xrow = x + (((size_t)(b * C_ + c0 + c)) << 12) + hw0;
    float* orow = out_q + (((size_t)(b * C_ + c0 + c)) << 12) + hw0;
#pragma unroll
    for (int j = 0; j < 8; ++j) {
      float q  = ecol[c][(kreg[j] + c0 + c) & 511];
      float xv = xrow[t + 256 * j];
      orow[t + 256 * j] = q;
      double d = (double)q - (double)xv;
      s += d * d;
    }
  }
  for (int off = 32; off > 0; off >>= 1) s += __shfl_down(s, off, 64);
  __shared__ double wsum[4];
  if ((t & 63) == 0) wsum[t >> 6] = s;
  __syncthreads();
  if (t == 0)
    loss_part[bid] = (wsum[0] + wsum[1]) + (wsum[2] + wsum[3]);
}

// ---------------------------------------------------------------------------
// K4: per-batch unique-code count + write idx_b as float.
// ---------------------------------------------------------------------------
__global__ __launch_bounds__(256) void k_pplx(const int* __restrict__ idx,
    float* __restrict__ out_idxf, int* __restrict__ counts)
{
  __shared__ int flags[K_];
  __shared__ int red[256];
  int b = blockIdx.x;
  for (int i = threadIdx.x; i < K_; i += 256) flags[i] = 0;
  __syncthreads();
  for (int hw = threadIdx.x; hw < HW_; hw += 256) {
    int k = idx[(b << 12) + hw];
    flags[k] = 1;
    out_idxf[(b << 12) + hw] = (float)k;
  }
  __syncthreads();
  int c = 0;
  for (int i = threadIdx.x; i < K_; i += 256) c += flags[i];
  red[threadIdx.x] = c;
  __syncthreads();
  for (int st = 128; st > 0; st >>= 1) {
    if (threadIdx.x < st) red[threadIdx.x] += red[threadIdx.x + st];
    __syncthreads();
  }
  if (threadIdx.x == 0) counts[b] = red[0];
}

// ---------------------------------------------------------------------------
// K5: finalize scalars (1024 loss partials).
// ---------------------------------------------------------------------------
__global__ __launch_bounds__(256) void k_final(const double* __restrict__ loss_part,
    const int* __restrict__ counts, float* __restrict__ out_loss,
    float* __restrict__ out_pplx)
{
  __shared__ double sred[256];
  double s = 0.0;
  for (int i = threadIdx.x; i < 1024; i += 256) s += loss_part[i];
  sred[threadIdx.x] = s;
  __syncthreads();
  for (int st = 128; st > 0; st >>= 1) {
    if (threadIdx.x < st) sred[threadIdx.x] += sred[threadIdx.x + st];
    __syncthreads();
  }
  if (threadIdx.x == 0) {
    *out_loss = (float)(1.25 * sred[0] / (double)QELEMS);
    int c = 0;
    for (int i = 0; i < B_; ++i) c += counts[i];
    *out_pplx = (float)c / (float)B_;
  }
}

// ---------------------------------------------------------------------------
extern "C" void kernel_launch(void* const* d_in, const int* in_sizes, int n_in,
                              void* d_out, int out_size, void* d_ws, size_t ws_size,
                              hipStream_t stream)
{
  const float* x     = (const float*)d_in[0];
  const float* embed = (const float*)d_in[1];
  float* out      = (float*)d_out;
  float* out_loss = out;                  // [0]
  float* out_q    = out + 1;              // [1 .. 1+QELEMS)
  float* out_pplx = out + 1 + QELEMS;     // [1+QELEMS]
  float* out_idxf = out + 2 + QELEMS;     // [2+QELEMS ..)

  char* ws = (char*)d_ws;
  int*    w_idx = (int*)ws;
  double* w_lp  = (double*)(ws + 524288);
  int*    w_cnt = (int*)(ws + 524288 + 16384);
  size_t pers = 524288 + 16384 + 128;

  const size_t OFF_EFR  = 134217728;               // xfrag 134 MB
  const size_t OFF_SENP = OFF_EFR + 524288;        // efrag 512 KB
  const size_t OFF_RCNT = OFF_SENP + 2048;
  const size_t OFF_RROW = OFF_RCNT + 256;
  const size_t VOLB     = OFF_RROW + (size_t)RFCAP * 4;
  char* vbase;
  if (ws_size >= pers + VOLB + 4096) {
    vbase = ws + ((pers + 255) & ~(size_t)255);
  } else {
    uintptr_t a = ((uintptr_t)(out_q + QELEMS) - VOLB) & ~(uintptr_t)255;
    vbase = (char*)a;
  }
  ushort* w_xfr  = (ushort*)vbase;
  ushort* w_efr  = (ushort*)(vbase + OFF_EFR);
  float*  w_senp = (float*)(vbase + OFF_SENP);
  int*    w_rcnt = (int*)(vbase + OFF_RCNT);
  int*    w_rrows= (int*)(vbase + OFF_RROW);

  k_prep  <<<dim3(512),   dim3(256), 0, stream>>>(embed, w_senp, w_rcnt);
  k_epack <<<dim3(16),    dim3(256), 0, stream>>>(embed, w_efr);
  k_xsplit<<<dim3(16384), dim3(256), 0, stream>>>(x, w_xfr);
  k_argmin<<<dim3(2048),  dim3(512), 0, stream>>>(w_xfr, w_efr, w_senp, w_idx, w_rcnt, w_rrows);
  k_refine<<<dim3(2048),  dim3(512), 0, stream>>>(x, embed, w_senp, w_rcnt, w_rrows, w_idx);
  k_gather<<<dim3(1024),  dim3(256), 0, stream>>>(x, embed, w_idx, out_q, w_lp);
  k_pplx  <<<dim3(32),    dim3(256), 0, stream>>>(w_idx, out_idxf, w_cnt);
  k_final <<<dim3(1),     dim3(256), 0, stream>>>(w_lp, w_cnt, out_loss, out_pplx);
}